// Round 21
// baseline (389.190 us; speedup 1.0000x reference)
//
#include <hip/hip_runtime.h>
#include <hip/hip_bf16.h>
#include <hip/hip_fp8.h>
#include <stdint.h>

typedef unsigned short u16;
typedef __attribute__((ext_vector_type(8))) short bf16x8;
typedef __attribute__((ext_vector_type(4))) unsigned short u16x4;
typedef __attribute__((ext_vector_type(4))) float f32x4;
typedef __attribute__((ext_vector_type(2))) long lx2;

#define AS1 __attribute__((address_space(1)))
#define AS3 __attribute__((address_space(3)))

__device__ __forceinline__ u16 f2bf(float f) {
  uint32_t x = __float_as_uint(f);
  uint32_t r = (x + 0x7FFFu + ((x >> 16) & 1u)) >> 16;
  return (u16)r;
}
__device__ __forceinline__ float bf2f(u16 u) {
  return __uint_as_float(((uint32_t)u) << 16);
}
__device__ __forceinline__ uint8_t f2f8(float f) {
  __hip_fp8_e4m3 t(f);
  return (uint8_t)t.__x;
}
__device__ __forceinline__ float f82f(uint8_t v) {
  __hip_fp8_e4m3 t;
  t.__x = (__hip_fp8_storage_t)v;
  return (float)t;
}

// K-permutation within each 64-col group: 8B subgroup s -> s' = 2(s&3)+(s>>2).
__device__ __forceinline__ int permcol(int c) {
  return (c & ~63) | (((c >> 3) & 3) << 4) | (((c >> 5) & 1) << 3) | (c & 7);
}

__device__ __forceinline__ void gload_lds16(const void* g, void* l) {
  __builtin_amdgcn_global_load_lds((const AS1 void*)g, (AS3 void*)l, 16, 0, 0);
}

// ---- fused 3x3 avg pool + transpose + bf16: in[b][c][hw] -> PT[(b,hw)][C] ----
template <int C, int H, int W>
__global__ __launch_bounds__(256) void pool_trans(const float* __restrict__ in,
                                                  u16* __restrict__ PT) {
  constexpr int HW = H * W;
  int hwt = blockIdx.x, ct = blockIdx.y, b = blockIdx.z;
  int tid = threadIdx.x;
  __shared__ float t[32][33];
  {
    int c_l = tid >> 3;
    int hw_l = (tid & 7) * 4;
    int c = ct * 32 + c_l;
    int hw = hwt * 32 + hw_l;
    int y = hw / W;
    int x0 = hw % W;
    const float* pl = in + ((size_t)b * C + c) * HW;
    float cs[6] = {0, 0, 0, 0, 0, 0};
    #pragma unroll
    for (int dy = -1; dy <= 1; dy++) {
      int yy = y + dy;
      if ((unsigned)yy < (unsigned)H) {
        const float* row = pl + yy * W;
        #pragma unroll
        for (int k = 0; k < 6; k++) {
          int xx = x0 - 1 + k;
          if ((unsigned)xx < (unsigned)W) cs[k] += row[xx];
        }
      }
    }
    #pragma unroll
    for (int k = 0; k < 4; k++)
      t[c_l][hw_l + k] = (cs[k] + cs[k + 1] + cs[k + 2]) * (1.0f / 9.0f);
  }
  __syncthreads();
  int hw_w = tid >> 3;
  int c_w = (tid & 7) * 4;
  u16x4 o;
  #pragma unroll
  for (int j = 0; j < 4; j++) o[j] = f2bf(t[c_w + j][hw_w]);
  *(u16x4*)&PT[((size_t)b * HW + hwt * 32 + hw_w) * C + ct * 32 + c_w] = o;
}

// ---------------- w[O][K+2] fp32 -> Wb[O][K] bf16 ----------------
__global__ void wconv_bf16(const float* __restrict__ wf, u16* __restrict__ wb,
                           int logk, int total) {
  int idx = blockIdx.x * 256 + threadIdx.x;
  if (idx >= total) return;
  int K = 1 << logk;
  int o = idx >> (logk - 3);
  int k0 = (idx & ((K >> 3) - 1)) * 8;
  const float* src = wf + (size_t)o * (K + 2) + k0;
  bf16x8 v;
  #pragma unroll
  for (int e = 0; e < 8; e++) v[e] = (short)f2bf(src[e]);
  *(bf16x8*)&wb[(size_t)o * K + k0] = v;
}

// ======== MFMA CoordConv GEMM, dual-layout epilogue ========
template <int K, int HW, int WD, int OC, int PHIC, int CST, bool OUT8>
__global__ __launch_bounds__(256) void conv_gemm(
    const u16* __restrict__ Wb,   // [OC][K] bf16
    const u16* __restrict__ PT,   // [4*HW][K] bf16
    const float* __restrict__ wf, // [OC][K+2] fp32 (coord cols)
    const float* __restrict__ bias,
    float* __restrict__ outHW, size_t outHW_bstride,
    void* __restrict__ outCM) {
  constexpr int LOGW = (WD == 64) ? 6 : (WD == 32) ? 5 : 4;
  constexpr int LOGHW = 2 * LOGW;
  int n0 = blockIdx.x * 128, m0 = blockIdx.y * 128;
  int tid = threadIdx.x;
  int wid = tid >> 6, lane = tid & 63;
  int wm = wid >> 1, wn = wid & 1;
  __shared__ u16 As[128 * 64];
  __shared__ u16 Bs[128 * 64];
  f32x4 acc[4][4] = {};
  int lrow = tid >> 3;
  int lcol = (tid & 7) * 8;
  const u16* ga = Wb + (size_t)(m0 + lrow) * K + lcol;
  const u16* gb = PT + (size_t)(n0 + lrow) * K + lcol;
  char* lbaseA = (char*)As + wid * 1024;
  char* lbaseB = (char*)Bs + wid * 1024;
  for (int k0 = 0; k0 < K; k0 += 64) {
    #pragma unroll
    for (int q = 0; q < 4; q++) {
      gload_lds16(ga + (size_t)q * 32 * K + k0, lbaseA + q * 4096);
      gload_lds16(gb + (size_t)q * 32 * K + k0, lbaseB + q * 4096);
    }
    __syncthreads();
    #pragma unroll
    for (int kk = 0; kk < 2; kk++) {
      bf16x8 af[4], bfr[4];
      int kb = kk * 32 + (lane >> 4) * 8;
      #pragma unroll
      for (int i = 0; i < 4; i++)
        af[i] = *(const bf16x8*)&As[(wm * 64 + i * 16 + (lane & 15)) * 64 + kb];
      #pragma unroll
      for (int j = 0; j < 4; j++)
        bfr[j] = *(const bf16x8*)&Bs[(wn * 64 + j * 16 + (lane & 15)) * 64 + kb];
      #pragma unroll
      for (int i = 0; i < 4; i++)
        #pragma unroll
        for (int j = 0; j < 4; j++)
          acc[i][j] = __builtin_amdgcn_mfma_f32_16x16x32_bf16(af[i], bfr[j], acc[i][j], 0, 0, 0);
    }
    __syncthreads();
  }
  int rq = lane >> 4, cq = lane & 15;
  #pragma unroll
  for (int mi = 0; mi < 4; mi++) {
    int lm = m0 + wm * 64 + mi * 16 + rq * 4;
    float wxr[4], wyr[4], bbr[4];
    #pragma unroll
    for (int r = 0; r < 4; r++) {
      int o = lm + r;
      wxr[r] = wf[(size_t)o * (K + 2) + K];
      wyr[r] = wf[(size_t)o * (K + 2) + K + 1];
      bbr[r] = bias[o];
    }
    #pragma unroll
    for (int ni = 0; ni < 4; ni++) {
      int gn = n0 + wn * 64 + ni * 16 + cq;
      int b = gn >> LOGHW;
      int hw = gn & (HW - 1);
      int x = hw & (WD - 1), y = hw >> LOGW;
      float xg = -1.0f + x * (2.0f / (WD - 1));
      float yg = -1.0f + y * (2.0f / (WD - 1));
      float vals[4];
      #pragma unroll
      for (int r = 0; r < 4; r++)
        vals[r] = acc[mi][ni][r] + wxr[r] * xg + wyr[r] * yg + bbr[r];
      if (lm < PHIC) {
        #pragma unroll
        for (int r = 0; r < 4; r++)
          outHW[(size_t)b * outHW_bstride + (size_t)(lm + r) * HW + hw] = vals[r];
      }
      if constexpr (OUT8) {
        uint32_t pk = (uint32_t)f2f8(vals[0]) | ((uint32_t)f2f8(vals[1]) << 8) |
                      ((uint32_t)f2f8(vals[2]) << 16) | ((uint32_t)f2f8(vals[3]) << 24);
        *(uint32_t*)&((uint8_t*)outCM)[((size_t)b * HW + hw) * CST + permcol(lm)] = pk;
      } else {
        u16x4 pk;
        #pragma unroll
        for (int r = 0; r < 4; r++) pk[r] = f2bf(vals[r]);
        *(u16x4*)&((u16*)outCM)[((size_t)b * HW + hw) * CST + lm] = pk;
      }
    }
  }
}

// bilinear helpers (half-pixel, edge clamp)
template <int Hin>
__device__ __forceinline__ void bilin_coords(int v, int& i0, int& i1, float& wgt) {
  constexpr float scale = (float)Hin / 64.0f;
  float f = ((float)v + 0.5f) * scale - 0.5f;
  float f0 = floorf(f);
  wgt = f - f0;
  int i = (int)f0;
  i1 = min(i + 1, Hin - 1);
  i0 = max(i, 0);
}

// ---------------- emit out_phi (fp32, hw fastest) — 4 px/thread ----------------
template <int C, int Cin, int Hin>
__global__ void emit_phi_v(const float* __restrict__ in, float* __restrict__ outp,
                           int ch_off) {
  int idx = blockIdx.x * 256 + threadIdx.x;
  int x0 = (idx & 15) * 4;
  int y = (idx >> 4) & 63;
  int c = (idx >> 10) % C;
  int b = idx / (C * 1024);
  const float* pl = in + (size_t)(b * Cin + c) * (Hin * Hin);
  int y0, y1; float wy;
  bilin_coords<Hin>(y, y0, y1, wy);
  const float* r0 = pl + y0 * Hin;
  const float* r1 = pl + y1 * Hin;
  f32x4 o;
  #pragma unroll
  for (int k = 0; k < 4; k++) {
    int xx0, xx1; float wx;
    bilin_coords<Hin>(x0 + k, xx0, xx1, wx);
    float top = (1.0f - wx) * r0[xx0] + wx * r0[xx1];
    float bot = (1.0f - wx) * r1[xx0] + wx * r1[xx1];
    o[k] = (1.0f - wy) * top + wy * bot;
  }
  *(f32x4*)&outp[((size_t)b * 896 + ch_off + c) * 4096 + (y << 6) + x0] = o;
}

// ---------------- fp32 [R][Cc] -> fp8 [c][permcol(r)] transpose ----------------
__global__ __launch_bounds__(256) void trans_f32_fp8(
    const float* __restrict__ in, uint8_t* __restrict__ outT, int R, int Cc, int OS) {
  int r0 = blockIdx.y * 32, c0 = blockIdx.x * 32;
  __shared__ float t[32][33];
  int tid = threadIdx.x;
  int cl = tid & 31, rl = tid >> 5;
  #pragma unroll
  for (int q = 0; q < 4; q++)
    t[rl + q * 8][cl] = in[(size_t)(r0 + rl + q * 8) * Cc + c0 + cl];
  __syncthreads();
  #pragma unroll
  for (int q = 0; q < 4; q++) {
    int c = c0 + rl + q * 8;
    outT[(size_t)c * OS + permcol(r0 + cl)] = f2f8(t[cl][rl + q * 8]);
  }
}

// ---------------- gather A from OT[b][p][C] (bf16) -> fp8 at permuted cols ----------------
template <int C, int Hin, int L>
__global__ void gather_A(const u16* __restrict__ OT, uint8_t* __restrict__ A,
                         int ch_off) {
  int idx = blockIdx.x * 256 + threadIdx.x;
  int co = (idx & ((C / 8) - 1)) * 8;
  int hw = (idx >> L) & 4095;
  int b = idx >> (L + 12);
  int x = hw & 63, y = hw >> 6;
  int y0, y1, x0, x1; float wy, wx;
  bilin_coords<Hin>(y, y0, y1, wy);
  bilin_coords<Hin>(x, x0, x1, wx);
  float w00 = (1.0f - wy) * (1.0f - wx), w01 = (1.0f - wy) * wx;
  float w10 = wy * (1.0f - wx), w11 = wy * wx;
  const u16* base = OT + (size_t)b * (Hin * Hin) * C + co;
  bf16x8 t00 = *(const bf16x8*)&base[(y0 * Hin + x0) * C];
  bf16x8 t01 = *(const bf16x8*)&base[(y0 * Hin + x1) * C];
  bf16x8 t10 = *(const bf16x8*)&base[(y1 * Hin + x0) * C];
  bf16x8 t11 = *(const bf16x8*)&base[(y1 * Hin + x1) * C];
  uint32_t pk[2] = {0, 0};
  #pragma unroll
  for (int e = 0; e < 8; e++) {
    float v = w00 * bf2f((u16)t00[e]) + w01 * bf2f((u16)t01[e]) +
              w10 * bf2f((u16)t10[e]) + w11 * bf2f((u16)t11[e]);
    pk[e >> 2] |= ((uint32_t)f2f8(v)) << ((e & 3) * 8);
  }
  uint2 o; o.x = pk[0]; o.y = pk[1];
  *(uint2*)&A[((size_t)b * 4096 + hw) * 1792 + permcol(ch_off + co)] = o;
}

// ---------------- row sum of squares over fp8 rows (order-independent) ----------------
__global__ __launch_bounds__(256) void rownorm8(const uint8_t* __restrict__ X,
                                                float* __restrict__ out, int ncols) {
  int row = blockIdx.x * 4 + (threadIdx.x >> 6);
  int lane = threadIdx.x & 63;
  const uint8_t* xr = X + (size_t)row * ncols;
  int n8 = ncols >> 3;
  float s = 0.0f;
  for (int c8 = lane; c8 < n8; c8 += 64) {
    uint2 v = *(const uint2*)&xr[c8 * 8];
    #pragma unroll
    for (int e = 0; e < 4; e++) {
      float f = f82f((uint8_t)((v.x >> (8 * e)) & 0xFF));
      s = fmaf(f, f, s);
    }
    #pragma unroll
    for (int e = 0; e < 4; e++) {
      float f = f82f((uint8_t)((v.y >> (8 * e)) & 0xFF));
      s = fmaf(f, f, s);
    }
  }
  #pragma unroll
  for (int off = 32; off; off >>= 1) s += __shfl_down(s, off);
  if (lane == 0) out[row] = s;
}

// ======== fp8 distance GEMM: 256x128 tile, 4 waves, 2 blocks/CU, ring-3 ========
// Counted vmcnt(6): tile t+1's 6 per-wave loads stay in flight across the
// barrier (T4). Ring-3 LDS = 72 KiB/block -> 2 blocks/CU (144 <= 160 KiB).
#define GD_NT 28  // K/64

__device__ __forceinline__ void stageA2(const uint8_t* __restrict__ G, int row0,
                                        int k0, char* dest, int lane) {
  const int K = 1792;
  int sub = lane >> 2;
  int colsw = 16 * ((lane & 3) ^ ((lane >> 3) & 3));
  #pragma unroll
  for (int q = 0; q < 4; q++)
    gload_lds16(G + (size_t)(row0 + q * 64 + sub) * K + k0 + colsw, dest + q * 4096);
}
__device__ __forceinline__ void stageB2(const uint8_t* __restrict__ G, int row0,
                                        int k0, char* dest, int lane) {
  const int K = 1792;
  int sub = lane >> 2;
  int colsw = 16 * ((lane & 3) ^ ((lane >> 3) & 3));
  #pragma unroll
  for (int q = 0; q < 2; q++)
    gload_lds16(G + (size_t)(row0 + q * 64 + sub) * K + k0 + colsw, dest + q * 4096);
}

__global__ __launch_bounds__(256, 2) void gemm_dist2(
    const uint8_t* __restrict__ A,   // [16384][1792] fp8 (K-permuted)
    const uint8_t* __restrict__ Bt,  // [4096][1792] fp8 (K-permuted)
    const float* __restrict__ feats, const float* __restrict__ cents,
    u16* __restrict__ S16, int m_base) {
  const int K = 1792, N = 4096;
  extern __shared__ uint8_t lds8[];  // 3 bufs x (A 16KB + B 8KB) = 72 KiB
  int bid = blockIdx.x;
  int swz = (bid & 7) * 128 + (bid >> 3);
  int m0 = (swz >> 5) * 256;   // 0..31
  int n0 = (swz & 31) * 128;   // 0..31
  int tid = threadIdx.x;
  int wid = tid >> 6, lane = tid & 63;
  int wr = wid >> 1, wc = wid & 1;  // wave -> 128x64 output sub-tile
  int ln15 = lane & 15;
  int fo = 16 * ((lane >> 4) ^ ((lane >> 1) & 3));  // phys 16B slot (row>>1 swizzle)

  f32x4 acc[8][4] = {};

  // prologue: stage tiles 0,1 (12 loads/wave outstanding)
  #pragma unroll
  for (int t = 0; t < 2; t++) {
    char* bufb = (char*)lds8 + t * 24576;
    stageA2(A, m_base + m0 + wid * 16, t * 64, bufb + wid * 1024, lane);
    stageB2(Bt, n0 + wid * 16, t * 64, bufb + 16384 + wid * 1024, lane);
  }

  int cb = 0;  // t % 3
  #pragma unroll 1
  for (int t = 0; t < GD_NT - 1; t++) {
    // tile t landed iff <=6 newest loads (tile t+1's) remain in flight
    asm volatile("s_waitcnt vmcnt(6)" ::: "memory");
    __builtin_amdgcn_s_barrier();
    __builtin_amdgcn_sched_barrier(0);
    const uint8_t* Ab = lds8 + cb * 24576;
    const uint8_t* Bb = Ab + 16384;
    int nbidx = cb + 2; if (nbidx >= 3) nbidx -= 3;  // (t+2) % 3
    char* nb = (char*)lds8 + nbidx * 24576;

    lx2 bq[4], af[8];
    #pragma unroll
    for (int ni = 0; ni < 4; ni++)
      bq[ni] = *(const lx2*)&Bb[(wc * 64 + ni * 16 + ln15) * 64 + fo];
    #pragma unroll
    for (int mi = 0; mi < 8; mi++)
      af[mi] = *(const lx2*)&Ab[(wr * 128 + mi * 16 + ln15) * 64 + fo];

    if (t + 2 < GD_NT) {
      stageA2(A, m_base + m0 + wid * 16, (t + 2) * 64, nb + wid * 1024, lane);
      stageB2(Bt, n0 + wid * 16, (t + 2) * 64, nb + 16384 + wid * 1024, lane);
    }

    __builtin_amdgcn_s_setprio(1);
    #pragma unroll
    for (int mi = 0; mi < 8; mi++)
      #pragma unroll
      for (int ni = 0; ni < 4; ni++)
        acc[mi][ni] = __builtin_amdgcn_mfma_f32_16x16x32_fp8_fp8(af[mi][0], bq[ni][0], acc[mi][ni], 0, 0, 0);
    #pragma unroll
    for (int mi = 0; mi < 8; mi++)
      #pragma unroll
      for (int ni = 0; ni < 4; ni++)
        acc[mi][ni] = __builtin_amdgcn_mfma_f32_16x16x32_fp8_fp8(af[mi][1], bq[ni][1], acc[mi][ni], 0, 0, 0);
    __builtin_amdgcn_s_setprio(0);

    cb++; if (cb >= 3) cb -= 3;
  }

  // peeled last tile: nothing newer in flight -> full drain
  {
    asm volatile("s_waitcnt vmcnt(0)" ::: "memory");
    __builtin_amdgcn_s_barrier();
    __builtin_amdgcn_sched_barrier(0);
    const uint8_t* Ab = lds8 + cb * 24576;
    const uint8_t* Bb = Ab + 16384;
    lx2 bq[4], af[8];
    #pragma unroll
    for (int ni = 0; ni < 4; ni++)
      bq[ni] = *(const lx2*)&Bb[(wc * 64 + ni * 16 + ln15) * 64 + fo];
    #pragma unroll
    for (int mi = 0; mi < 8; mi++)
      af[mi] = *(const lx2*)&Ab[(wr * 128 + mi * 16 + ln15) * 64 + fo];
    __builtin_amdgcn_s_setprio(1);
    #pragma unroll
    for (int mi = 0; mi < 8; mi++)
      #pragma unroll
      for (int ni = 0; ni < 4; ni++)
        acc[mi][ni] = __builtin_amdgcn_mfma_f32_16x16x32_fp8_fp8(af[mi][0], bq[ni][0], acc[mi][ni], 0, 0, 0);
    #pragma unroll
    for (int mi = 0; mi < 8; mi++)
      #pragma unroll
      for (int ni = 0; ni < 4; ni++)
        acc[mi][ni] = __builtin_amdgcn_mfma_f32_16x16x32_fp8_fp8(af[mi][1], bq[ni][1], acc[mi][ni], 0, 0, 0);
    __builtin_amdgcn_s_setprio(0);
  }

  int rq = lane >> 4, cq = lane & 15;
  #pragma unroll
  for (int mi = 0; mi < 8; mi++) {
    int lm = m0 + wr * 128 + mi * 16 + rq * 4;
    #pragma unroll
    for (int ni = 0; ni < 4; ni++) {
      int gn = n0 + wc * 64 + ni * 16 + cq;
      float cn = cents[gn];
      #pragma unroll
      for (int r = 0; r < 4; r++)
        S16[(size_t)(lm + r) * N + gn] =
            f2bf(feats[m_base + lm + r] + cn - 2.0f * acc[mi][ni][r]);
    }
  }
}

// ---------------- per-row top-200 smallest (sorted) of 4096 bf16 keys ----------------
__global__ __launch_bounds__(256) void select_topk(const u16* __restrict__ S16,
                                                   float* __restrict__ out,
                                                   int row_base) {
  int wv = threadIdx.x >> 6, lane = threadIdx.x & 63;
  int row_local = blockIdx.x * 4 + wv;
  const u16* Sr = S16 + (size_t)row_local * 4096;
  uint32_t ku[64];
  #pragma unroll
  for (int g = 0; g < 8; g++) {
    bf16x8 v = *(const bf16x8*)&Sr[g * 512 + lane * 8];
    #pragma unroll
    for (int e = 0; e < 8; e++) {
      uint32_t u = (uint32_t)(u16)v[e];
      u ^= (u & 0x8000u) ? 0xFFFFu : 0x8000u;
      ku[g * 8 + e] = u;
    }
  }
  uint32_t mn = 0xFFFFu, mx = 0u;
  #pragma unroll
  for (int j = 0; j < 64; j++) {
    mn = min(mn, ku[j]);
    mx = max(mx, ku[j]);
  }
  #pragma unroll
  for (int off = 1; off < 64; off <<= 1) {
    mn = min(mn, (uint32_t)__shfl_xor((int)mn, off));
    mx = max(mx, (uint32_t)__shfl_xor((int)mx, off));
  }
  uint32_t lo = mn, hi = mx;
  while (lo < hi) {
    uint32_t mid = (lo + hi) >> 1;
    int c = 0;
    #pragma unroll
    for (int j = 0; j < 64; j++) c += (ku[j] <= mid) ? 1 : 0;
    #pragma unroll
    for (int off = 1; off < 64; off <<= 1) c += __shfl_xor(c, off);
    if (c >= 200) hi = mid; else lo = mid + 1;
  }
  uint32_t T = lo;
  int cl = 0;
  #pragma unroll
  for (int j = 0; j < 64; j++) cl += (ku[j] < T) ? 1 : 0;
  int incl = cl;
  #pragma unroll
  for (int off = 1; off < 64; off <<= 1) {
    int v = __shfl_up(incl, off);
    if (lane >= off) incl += v;
  }
  int nless = __shfl(incl, 63);
  int pos = incl - cl;
  __shared__ uint32_t selv[4][256];
  uint32_t* sv = selv[wv];
  #pragma unroll
  for (int g = 0; g < 4; g++) sv[g * 64 + lane] = 0xFFFFFFFFu;
  for (int p = nless + lane; p < 200; p += 64) sv[p] = T;
  #pragma unroll
  for (int j = 0; j < 64; j++)
    if (ku[j] < T) sv[pos++] = ku[j];
  uint32_t v[4];
  #pragma unroll
  for (int q = 0; q < 4; q++) v[q] = sv[q * 64 + lane];
  #pragma unroll
  for (int kk = 2; kk <= 256; kk <<= 1) {
    #pragma unroll
    for (int jj = kk >> 1; jj > 0; jj >>= 1) {
      if (jj >= 64) {
        int qb = jj >> 6;
        #pragma unroll
        for (int q = 0; q < 4; q++) {
          if ((q & qb) == 0) {
            int q2 = q | qb;
            bool up = (kk == 256) ? true : ((q & (kk >> 6)) == 0);
            uint32_t a = v[q], b2 = v[q2];
            uint32_t lo2 = min(a, b2), hi2 = max(a, b2);
            v[q] = up ? lo2 : hi2;
            v[q2] = up ? hi2 : lo2;
          }
        }
      } else {
        #pragma unroll
        for (int q = 0; q < 4; q++) {
          bool up;
          if (kk == 256) up = true;
          else if (kk == 128) up = ((q & 2) == 0);
          else if (kk == 64) up = ((q & 1) == 0);
          else up = ((lane & kk) == 0);
          uint32_t other = (uint32_t)__shfl_xor((int)v[q], jj);
          bool lower = ((lane & jj) == 0);
          uint32_t lo2 = min(v[q], other), hi2 = max(v[q], other);
          v[q] = (up == lower) ? lo2 : hi2;
        }
      }
    }
  }
  int grow = row_base + row_local;
  int b = grow >> 12, r = grow & 4095;
  #pragma unroll
  for (int q = 0; q < 4; q++) {
    int i = q * 64 + lane;
    if (i < 200) {
      uint32_t u = v[q] & 0xFFFFu;
      u ^= (u & 0x8000u) ? 0x8000u : 0xFFFFu;
      out[((size_t)b * 200 + i) * 4096 + r] = sqrtf(bf2f((u16)u));
    }
  }
}

extern "C" void kernel_launch(void* const* d_in, const int* in_sizes, int n_in,
                              void* d_out, int out_size, void* d_ws, size_t ws_size,
                              hipStream_t stream) {
  const float* p0 = (const float*)d_in[0];   // (4,256,64,64)
  const float* p1 = (const float*)d_in[1];   // (4,512,32,32)
  const float* p2 = (const float*)d_in[2];   // (4,1024,16,16)
  const float* w1 = (const float*)d_in[5];   // (256,258)
  const float* b1 = (const float*)d_in[6];
  const float* w2 = (const float*)d_in[7];   // (512,514)
  const float* b2 = (const float*)d_in[8];
  const float* w3 = (const float*)d_in[9];   // (1024,1026)
  const float* b3 = (const float*)d_in[10];
  const float* Cm = (const float*)d_in[11];  // (1792,4096)

  float* out_score = (float*)d_out;                  // 4*200*4096 fp32
  float* out_phi = (float*)d_out + 3276800;          // 4*896*4096 fp32

  // workspace layout (peak ~103.9 MB)
  char* w = (char*)d_ws;
  uint8_t* A8 = (uint8_t*)w;                         //  29,360,128 B [16384][1792] fp8
  uint8_t* Ct8 = (uint8_t*)(w + 29360128);           //   7,340,032 B [4096][1792] fp8
  float* feats = (float*)(w + 36700160);             //      65,536 B
  float* cents = (float*)(w + 36765696);             //      16,384 B
  u16* S16 = (u16*)(w + 36782080);                   //  67,108,864 B (bf16, 8192-row chunk) -> ends 103,890,944
  // stage-A temps alias the S16 region (dead before first gemm_dist2):
  u16* PT1 = (u16*)(w + 36782080);                   //   8,388,608 B [16384][256]
  u16* PT2 = (u16*)(w + 45170688);                   //   4,194,304 B [4096][512]
  u16* PT3 = (u16*)(w + 49364992);                   //   2,097,152 B [1024][1024]
  u16* Wbf1 = (u16*)(w + 51462144);                  //     131,072 B
  u16* Wbf2 = (u16*)(w + 51593216);                  //     524,288 B
  u16* Wbf3 = (u16*)(w + 52117504);                  //   2,097,152 B
  float* O2 = (float*)(w + 54214656);                //   8,388,608 B [4][512][1024]
  float* O3 = (float*)(w + 62603264);                //     524,288 B [4][128][256]
  u16* OT2 = (u16*)(w + 63127552);                   //   4,194,304 B [4][1024][512]
  u16* OT3 = (u16*)(w + 67321856);                   //   2,097,152 B [4][256][1024] -> ends 69,419,008

  // ---- fused pool + transpose + bf16 -> PT ----
  pool_trans<256, 64, 64><<<dim3(128, 8, 4), 256, 0, stream>>>(p0, PT1);
  pool_trans<512, 32, 32><<<dim3(32, 16, 4), 256, 0, stream>>>(p1, PT2);
  pool_trans<1024, 16, 16><<<dim3(8, 32, 4), 256, 0, stream>>>(p2, PT3);

  // ---- weights -> bf16 ----
  wconv_bf16<<<32, 256, 0, stream>>>(w1, Wbf1, 8, 8192);
  wconv_bf16<<<128, 256, 0, stream>>>(w2, Wbf2, 9, 32768);
  wconv_bf16<<<512, 256, 0, stream>>>(w3, Wbf3, 10, 131072);

  // ---- coordconv via MFMA GEMM, dual-layout epilogue ----
  conv_gemm<256, 4096, 64, 256, 256, 1792, true><<<dim3(128, 2), 256, 0, stream>>>(
      Wbf1, PT1, w1, b1, out_phi, (size_t)896 * 4096, A8);
  conv_gemm<512, 1024, 32, 512, 512, 512, false><<<dim3(32, 4), 256, 0, stream>>>(
      Wbf2, PT2, w2, b2, O2, (size_t)512 * 1024, OT2);
  conv_gemm<1024, 256, 16, 1024, 128, 1024, false><<<dim3(8, 8), 256, 0, stream>>>(
      Wbf3, PT3, w3, b3, O3, (size_t)128 * 256, OT3);

  // ---- out_phi levels 2,3 (bilinear resize) ----
  emit_phi_v<512, 512, 32><<<8192, 256, 0, stream>>>(O2, out_phi, 256);
  emit_phi_v<128, 128, 16><<<2048, 256, 0, stream>>>(O3, out_phi, 768);

  // ---- A8 cols [256,1792): coalesced gather from OT (bf16 taps -> fp8) ----
  gather_A<512, 32, 6><<<4096, 256, 0, stream>>>(OT2, A8, 256);
  gather_A<1024, 16, 7><<<8192, 256, 0, stream>>>(OT3, A8, 768);

  // ---- C transpose -> fp8 (permuted cols) ----
  trans_f32_fp8<<<dim3(128, 56), 256, 0, stream>>>(Cm, Ct8, 1792, 4096, 1792);

  // ---- norms (from the SAME fp8 data the GEMM sees) ----
  rownorm8<<<4096, 256, 0, stream>>>(A8, feats, 1792);
  rownorm8<<<1024, 256, 0, stream>>>(Ct8, cents, 1792);

  // ---- fp8 distance GEMM (ring-3, counted vmcnt, 2 blocks/CU) + top-200 ----
  for (int mc = 0; mc < 2; mc++) {
    gemm_dist2<<<1024, 256, 73728, stream>>>(A8, Ct8, feats, cents, S16, mc * 8192);
    select_topk<<<2048, 256, 0, stream>>>(S16, out_score, mc * 8192);
  }
}

// Round 22
// 381.682 us; speedup vs baseline: 1.0197x; 1.0197x over previous
//
#include <hip/hip_runtime.h>
#include <hip/hip_bf16.h>
#include <hip/hip_fp8.h>
#include <stdint.h>

typedef unsigned short u16;
typedef __attribute__((ext_vector_type(8))) short bf16x8;
typedef __attribute__((ext_vector_type(4))) unsigned short u16x4;
typedef __attribute__((ext_vector_type(4))) float f32x4;
typedef __attribute__((ext_vector_type(2))) long lx2;

#define AS1 __attribute__((address_space(1)))
#define AS3 __attribute__((address_space(3)))

__device__ __forceinline__ u16 f2bf(float f) {
  uint32_t x = __float_as_uint(f);
  uint32_t r = (x + 0x7FFFu + ((x >> 16) & 1u)) >> 16;
  return (u16)r;
}
__device__ __forceinline__ float bf2f(u16 u) {
  return __uint_as_float(((uint32_t)u) << 16);
}
__device__ __forceinline__ uint8_t f2f8(float f) {
  __hip_fp8_e4m3 t(f);
  return (uint8_t)t.__x;
}
__device__ __forceinline__ float f82f(uint8_t v) {
  __hip_fp8_e4m3 t;
  t.__x = (__hip_fp8_storage_t)v;
  return (float)t;
}

// K-permutation within each 64-col group: 8B subgroup s -> s' = 2(s&3)+(s>>2).
__device__ __forceinline__ int permcol(int c) {
  return (c & ~63) | (((c >> 3) & 3) << 4) | (((c >> 5) & 1) << 3) | (c & 7);
}

__device__ __forceinline__ void gload_lds16(const void* g, void* l) {
  __builtin_amdgcn_global_load_lds((const AS1 void*)g, (AS3 void*)l, 16, 0, 0);
}

// ---- fused 3x3 avg pool + transpose + bf16: in[b][c][hw] -> PT[(b,hw)][C] ----
template <int C, int H, int W>
__global__ __launch_bounds__(256) void pool_trans(const float* __restrict__ in,
                                                  u16* __restrict__ PT) {
  constexpr int HW = H * W;
  int hwt = blockIdx.x, ct = blockIdx.y, b = blockIdx.z;
  int tid = threadIdx.x;
  __shared__ float t[32][33];
  {
    int c_l = tid >> 3;
    int hw_l = (tid & 7) * 4;
    int c = ct * 32 + c_l;
    int hw = hwt * 32 + hw_l;
    int y = hw / W;
    int x0 = hw % W;
    const float* pl = in + ((size_t)b * C + c) * HW;
    float cs[6] = {0, 0, 0, 0, 0, 0};
    #pragma unroll
    for (int dy = -1; dy <= 1; dy++) {
      int yy = y + dy;
      if ((unsigned)yy < (unsigned)H) {
        const float* row = pl + yy * W;
        #pragma unroll
        for (int k = 0; k < 6; k++) {
          int xx = x0 - 1 + k;
          if ((unsigned)xx < (unsigned)W) cs[k] += row[xx];
        }
      }
    }
    #pragma unroll
    for (int k = 0; k < 4; k++)
      t[c_l][hw_l + k] = (cs[k] + cs[k + 1] + cs[k + 2]) * (1.0f / 9.0f);
  }
  __syncthreads();
  int hw_w = tid >> 3;
  int c_w = (tid & 7) * 4;
  u16x4 o;
  #pragma unroll
  for (int j = 0; j < 4; j++) o[j] = f2bf(t[c_w + j][hw_w]);
  *(u16x4*)&PT[((size_t)b * HW + hwt * 32 + hw_w) * C + ct * 32 + c_w] = o;
}

// ---------------- w[O][K+2] fp32 -> Wb[O][K] bf16 ----------------
__global__ void wconv_bf16(const float* __restrict__ wf, u16* __restrict__ wb,
                           int logk, int total) {
  int idx = blockIdx.x * 256 + threadIdx.x;
  if (idx >= total) return;
  int K = 1 << logk;
  int o = idx >> (logk - 3);
  int k0 = (idx & ((K >> 3) - 1)) * 8;
  const float* src = wf + (size_t)o * (K + 2) + k0;
  bf16x8 v;
  #pragma unroll
  for (int e = 0; e < 8; e++) v[e] = (short)f2bf(src[e]);
  *(bf16x8*)&wb[(size_t)o * K + k0] = v;
}

// ======== MFMA CoordConv GEMM, dual-layout epilogue ========
template <int K, int HW, int WD, int OC, int PHIC, int CST, bool OUT8>
__global__ __launch_bounds__(256) void conv_gemm(
    const u16* __restrict__ Wb,   // [OC][K] bf16
    const u16* __restrict__ PT,   // [4*HW][K] bf16
    const float* __restrict__ wf, // [OC][K+2] fp32 (coord cols)
    const float* __restrict__ bias,
    float* __restrict__ outHW, size_t outHW_bstride,
    void* __restrict__ outCM) {
  constexpr int LOGW = (WD == 64) ? 6 : (WD == 32) ? 5 : 4;
  constexpr int LOGHW = 2 * LOGW;
  int n0 = blockIdx.x * 128, m0 = blockIdx.y * 128;
  int tid = threadIdx.x;
  int wid = tid >> 6, lane = tid & 63;
  int wm = wid >> 1, wn = wid & 1;
  __shared__ u16 As[128 * 64];
  __shared__ u16 Bs[128 * 64];
  f32x4 acc[4][4] = {};
  int lrow = tid >> 3;
  int lcol = (tid & 7) * 8;
  const u16* ga = Wb + (size_t)(m0 + lrow) * K + lcol;
  const u16* gb = PT + (size_t)(n0 + lrow) * K + lcol;
  char* lbaseA = (char*)As + wid * 1024;
  char* lbaseB = (char*)Bs + wid * 1024;
  for (int k0 = 0; k0 < K; k0 += 64) {
    #pragma unroll
    for (int q = 0; q < 4; q++) {
      gload_lds16(ga + (size_t)q * 32 * K + k0, lbaseA + q * 4096);
      gload_lds16(gb + (size_t)q * 32 * K + k0, lbaseB + q * 4096);
    }
    __syncthreads();
    #pragma unroll
    for (int kk = 0; kk < 2; kk++) {
      bf16x8 af[4], bfr[4];
      int kb = kk * 32 + (lane >> 4) * 8;
      #pragma unroll
      for (int i = 0; i < 4; i++)
        af[i] = *(const bf16x8*)&As[(wm * 64 + i * 16 + (lane & 15)) * 64 + kb];
      #pragma unroll
      for (int j = 0; j < 4; j++)
        bfr[j] = *(const bf16x8*)&Bs[(wn * 64 + j * 16 + (lane & 15)) * 64 + kb];
      #pragma unroll
      for (int i = 0; i < 4; i++)
        #pragma unroll
        for (int j = 0; j < 4; j++)
          acc[i][j] = __builtin_amdgcn_mfma_f32_16x16x32_bf16(af[i], bfr[j], acc[i][j], 0, 0, 0);
    }
    __syncthreads();
  }
  int rq = lane >> 4, cq = lane & 15;
  #pragma unroll
  for (int mi = 0; mi < 4; mi++) {
    int lm = m0 + wm * 64 + mi * 16 + rq * 4;
    float wxr[4], wyr[4], bbr[4];
    #pragma unroll
    for (int r = 0; r < 4; r++) {
      int o = lm + r;
      wxr[r] = wf[(size_t)o * (K + 2) + K];
      wyr[r] = wf[(size_t)o * (K + 2) + K + 1];
      bbr[r] = bias[o];
    }
    #pragma unroll
    for (int ni = 0; ni < 4; ni++) {
      int gn = n0 + wn * 64 + ni * 16 + cq;
      int b = gn >> LOGHW;
      int hw = gn & (HW - 1);
      int x = hw & (WD - 1), y = hw >> LOGW;
      float xg = -1.0f + x * (2.0f / (WD - 1));
      float yg = -1.0f + y * (2.0f / (WD - 1));
      float vals[4];
      #pragma unroll
      for (int r = 0; r < 4; r++)
        vals[r] = acc[mi][ni][r] + wxr[r] * xg + wyr[r] * yg + bbr[r];
      if (lm < PHIC) {
        #pragma unroll
        for (int r = 0; r < 4; r++)
          outHW[(size_t)b * outHW_bstride + (size_t)(lm + r) * HW + hw] = vals[r];
      }
      if constexpr (OUT8) {
        uint32_t pk = (uint32_t)f2f8(vals[0]) | ((uint32_t)f2f8(vals[1]) << 8) |
                      ((uint32_t)f2f8(vals[2]) << 16) | ((uint32_t)f2f8(vals[3]) << 24);
        *(uint32_t*)&((uint8_t*)outCM)[((size_t)b * HW + hw) * CST + permcol(lm)] = pk;
      } else {
        u16x4 pk;
        #pragma unroll
        for (int r = 0; r < 4; r++) pk[r] = f2bf(vals[r]);
        *(u16x4*)&((u16*)outCM)[((size_t)b * HW + hw) * CST + lm] = pk;
      }
    }
  }
}

// bilinear helpers (half-pixel, edge clamp)
template <int Hin>
__device__ __forceinline__ void bilin_coords(int v, int& i0, int& i1, float& wgt) {
  constexpr float scale = (float)Hin / 64.0f;
  float f = ((float)v + 0.5f) * scale - 0.5f;
  float f0 = floorf(f);
  wgt = f - f0;
  int i = (int)f0;
  i1 = min(i + 1, Hin - 1);
  i0 = max(i, 0);
}

// ---------------- emit out_phi (fp32, hw fastest) — 4 px/thread ----------------
template <int C, int Cin, int Hin>
__global__ void emit_phi_v(const float* __restrict__ in, float* __restrict__ outp,
                           int ch_off) {
  int idx = blockIdx.x * 256 + threadIdx.x;
  int x0 = (idx & 15) * 4;
  int y = (idx >> 4) & 63;
  int c = (idx >> 10) % C;
  int b = idx / (C * 1024);
  const float* pl = in + (size_t)(b * Cin + c) * (Hin * Hin);
  int y0, y1; float wy;
  bilin_coords<Hin>(y, y0, y1, wy);
  const float* r0 = pl + y0 * Hin;
  const float* r1 = pl + y1 * Hin;
  f32x4 o;
  #pragma unroll
  for (int k = 0; k < 4; k++) {
    int xx0, xx1; float wx;
    bilin_coords<Hin>(x0 + k, xx0, xx1, wx);
    float top = (1.0f - wx) * r0[xx0] + wx * r0[xx1];
    float bot = (1.0f - wx) * r1[xx0] + wx * r1[xx1];
    o[k] = (1.0f - wy) * top + wy * bot;
  }
  *(f32x4*)&outp[((size_t)b * 896 + ch_off + c) * 4096 + (y << 6) + x0] = o;
}

// ---------------- fp32 [R][Cc] -> fp8 [c][permcol(r)] transpose ----------------
__global__ __launch_bounds__(256) void trans_f32_fp8(
    const float* __restrict__ in, uint8_t* __restrict__ outT, int R, int Cc, int OS) {
  int r0 = blockIdx.y * 32, c0 = blockIdx.x * 32;
  __shared__ float t[32][33];
  int tid = threadIdx.x;
  int cl = tid & 31, rl = tid >> 5;
  #pragma unroll
  for (int q = 0; q < 4; q++)
    t[rl + q * 8][cl] = in[(size_t)(r0 + rl + q * 8) * Cc + c0 + cl];
  __syncthreads();
  #pragma unroll
  for (int q = 0; q < 4; q++) {
    int c = c0 + rl + q * 8;
    outT[(size_t)c * OS + permcol(r0 + cl)] = f2f8(t[cl][rl + q * 8]);
  }
}

// ---------------- gather A from OT[b][p][C] (bf16) -> fp8 at permuted cols ----------------
template <int C, int Hin, int L>
__global__ void gather_A(const u16* __restrict__ OT, uint8_t* __restrict__ A,
                         int ch_off) {
  int idx = blockIdx.x * 256 + threadIdx.x;
  int co = (idx & ((C / 8) - 1)) * 8;
  int hw = (idx >> L) & 4095;
  int b = idx >> (L + 12);
  int x = hw & 63, y = hw >> 6;
  int y0, y1, x0, x1; float wy, wx;
  bilin_coords<Hin>(y, y0, y1, wy);
  bilin_coords<Hin>(x, x0, x1, wx);
  float w00 = (1.0f - wy) * (1.0f - wx), w01 = (1.0f - wy) * wx;
  float w10 = wy * (1.0f - wx), w11 = wy * wx;
  const u16* base = OT + (size_t)b * (Hin * Hin) * C + co;
  bf16x8 t00 = *(const bf16x8*)&base[(y0 * Hin + x0) * C];
  bf16x8 t01 = *(const bf16x8*)&base[(y0 * Hin + x1) * C];
  bf16x8 t10 = *(const bf16x8*)&base[(y1 * Hin + x0) * C];
  bf16x8 t11 = *(const bf16x8*)&base[(y1 * Hin + x1) * C];
  uint32_t pk[2] = {0, 0};
  #pragma unroll
  for (int e = 0; e < 8; e++) {
    float v = w00 * bf2f((u16)t00[e]) + w01 * bf2f((u16)t01[e]) +
              w10 * bf2f((u16)t10[e]) + w11 * bf2f((u16)t11[e]);
    pk[e >> 2] |= ((uint32_t)f2f8(v)) << ((e & 3) * 8);
  }
  uint2 o; o.x = pk[0]; o.y = pk[1];
  *(uint2*)&A[((size_t)b * 4096 + hw) * 1792 + permcol(ch_off + co)] = o;
}

// ---------------- row sum of squares over fp8 rows (order-independent) ----------------
__global__ __launch_bounds__(256) void rownorm8(const uint8_t* __restrict__ X,
                                                float* __restrict__ out, int ncols) {
  int row = blockIdx.x * 4 + (threadIdx.x >> 6);
  int lane = threadIdx.x & 63;
  const uint8_t* xr = X + (size_t)row * ncols;
  int n8 = ncols >> 3;
  float s = 0.0f;
  for (int c8 = lane; c8 < n8; c8 += 64) {
    uint2 v = *(const uint2*)&xr[c8 * 8];
    #pragma unroll
    for (int e = 0; e < 4; e++) {
      float f = f82f((uint8_t)((v.x >> (8 * e)) & 0xFF));
      s = fmaf(f, f, s);
    }
    #pragma unroll
    for (int e = 0; e < 4; e++) {
      float f = f82f((uint8_t)((v.y >> (8 * e)) & 0xFF));
      s = fmaf(f, f, s);
    }
  }
  #pragma unroll
  for (int off = 32; off; off >>= 1) s += __shfl_down(s, off);
  if (lane == 0) out[row] = s;
}

// ======== fp8 distance GEMM: 256x128 tile, 4 waves, 2 blocks/CU (ring-2) ========
#define GD_NT 28  // K/64

__device__ __forceinline__ void stageA2(const uint8_t* __restrict__ G, int row0,
                                        int k0, char* dest, int lane) {
  const int K = 1792;
  int sub = lane >> 2;
  int colsw = 16 * ((lane & 3) ^ ((lane >> 3) & 3));
  #pragma unroll
  for (int q = 0; q < 4; q++)
    gload_lds16(G + (size_t)(row0 + q * 64 + sub) * K + k0 + colsw, dest + q * 4096);
}
__device__ __forceinline__ void stageB2(const uint8_t* __restrict__ G, int row0,
                                        int k0, char* dest, int lane) {
  const int K = 1792;
  int sub = lane >> 2;
  int colsw = 16 * ((lane & 3) ^ ((lane >> 3) & 3));
  #pragma unroll
  for (int q = 0; q < 2; q++)
    gload_lds16(G + (size_t)(row0 + q * 64 + sub) * K + k0 + colsw, dest + q * 4096);
}

__global__ __launch_bounds__(256, 2) void gemm_dist2(
    const uint8_t* __restrict__ A,   // [16384][1792] fp8 (K-permuted)
    const uint8_t* __restrict__ Bt,  // [4096][1792] fp8 (K-permuted)
    const float* __restrict__ feats, const float* __restrict__ cents,
    u16* __restrict__ S16, int m_base) {
  const int K = 1792, N = 4096;
  extern __shared__ uint8_t lds8[];  // 2 bufs x (A 16KB + B 8KB) = 48 KiB
  int bid = blockIdx.x;
  int swz = (bid & 7) * 128 + (bid >> 3);
  int m0 = (swz >> 5) * 256;   // 0..31
  int n0 = (swz & 31) * 128;   // 0..31
  int tid = threadIdx.x;
  int wid = tid >> 6, lane = tid & 63;
  int wr = wid >> 1, wc = wid & 1;  // wave -> 128x64 output sub-tile
  int ln15 = lane & 15;
  int fo = 16 * ((lane >> 4) ^ ((lane >> 1) & 3));  // phys 16B slot (row>>1 swizzle)

  f32x4 acc[8][4] = {};

  // prologue: stage tile 0
  stageA2(A, m_base + m0 + wid * 16, 0, (char*)lds8 + wid * 1024, lane);
  stageB2(Bt, n0 + wid * 16, 0, (char*)lds8 + 16384 + wid * 1024, lane);

  #pragma unroll 1
  for (int t = 0; t < GD_NT; t++) {
    asm volatile("s_waitcnt vmcnt(0)" ::: "memory");
    __builtin_amdgcn_s_barrier();
    __builtin_amdgcn_sched_barrier(0);
    const uint8_t* Ab = lds8 + (t & 1) * 24576;
    const uint8_t* Bb = Ab + 16384;
    char* nb = (char*)lds8 + ((t + 1) & 1) * 24576;

    lx2 bq[4], af[8];
    #pragma unroll
    for (int ni = 0; ni < 4; ni++)
      bq[ni] = *(const lx2*)&Bb[(wc * 64 + ni * 16 + ln15) * 64 + fo];
    #pragma unroll
    for (int mi = 0; mi < 8; mi++)
      af[mi] = *(const lx2*)&Ab[(wr * 128 + mi * 16 + ln15) * 64 + fo];

    if (t + 1 < GD_NT) {
      stageA2(A, m_base + m0 + wid * 16, (t + 1) * 64, nb + wid * 1024, lane);
      stageB2(Bt, n0 + wid * 16, (t + 1) * 64, nb + 16384 + wid * 1024, lane);
    }

    __builtin_amdgcn_s_setprio(1);
    #pragma unroll
    for (int mi = 0; mi < 8; mi++)
      #pragma unroll
      for (int ni = 0; ni < 4; ni++)
        acc[mi][ni] = __builtin_amdgcn_mfma_f32_16x16x32_fp8_fp8(af[mi][0], bq[ni][0], acc[mi][ni], 0, 0, 0);
    #pragma unroll
    for (int mi = 0; mi < 8; mi++)
      #pragma unroll
      for (int ni = 0; ni < 4; ni++)
        acc[mi][ni] = __builtin_amdgcn_mfma_f32_16x16x32_fp8_fp8(af[mi][1], bq[ni][1], acc[mi][ni], 0, 0, 0);
    __builtin_amdgcn_s_setprio(0);
  }

  int rq = lane >> 4, cq = lane & 15;
  #pragma unroll
  for (int mi = 0; mi < 8; mi++) {
    int lm = m0 + wr * 128 + mi * 16 + rq * 4;
    #pragma unroll
    for (int ni = 0; ni < 4; ni++) {
      int gn = n0 + wc * 64 + ni * 16 + cq;
      float cn = cents[gn];
      #pragma unroll
      for (int r = 0; r < 4; r++)
        S16[(size_t)(lm + r) * N + gn] =
            f2bf(feats[m_base + lm + r] + cn - 2.0f * acc[mi][ni][r]);
    }
  }
}

// ---------------- per-row top-200 smallest (sorted) of 4096 bf16 keys ----------------
// wave-per-row; binary search counts via wave-uniform ballot+popcount (the
// v_cmp covers 64 keys/instr, s_bcnt runs on the scalar pipe, no shfl reduce).
__global__ __launch_bounds__(256) void select_topk(const u16* __restrict__ S16,
                                                   float* __restrict__ out,
                                                   int row_base) {
  int wv = threadIdx.x >> 6, lane = threadIdx.x & 63;
  int row_local = blockIdx.x * 4 + wv;
  const u16* Sr = S16 + (size_t)row_local * 4096;
  uint32_t ku[64];
  #pragma unroll
  for (int g = 0; g < 8; g++) {
    bf16x8 v = *(const bf16x8*)&Sr[g * 512 + lane * 8];
    #pragma unroll
    for (int e = 0; e < 8; e++) {
      uint32_t u = (uint32_t)(u16)v[e];
      u ^= (u & 0x8000u) ? 0xFFFFu : 0x8000u;
      ku[g * 8 + e] = u;
    }
  }
  uint32_t mn = 0xFFFFu, mx = 0u;
  #pragma unroll
  for (int j = 0; j < 64; j++) {
    mn = min(mn, ku[j]);
    mx = max(mx, ku[j]);
  }
  #pragma unroll
  for (int off = 1; off < 64; off <<= 1) {
    mn = min(mn, (uint32_t)__shfl_xor((int)mn, off));
    mx = max(mx, (uint32_t)__shfl_xor((int)mx, off));
  }
  // binary search for the 200th smallest ordinal T — ballot counting
  uint32_t lo = mn, hi = mx;
  while (lo < hi) {
    uint32_t mid = (lo + hi) >> 1;
    int c = 0;
    #pragma unroll
    for (int j = 0; j < 64; j++)
      c += (int)__popcll(__ballot(ku[j] <= mid));
    if (c >= 200) hi = mid; else lo = mid + 1;
  }
  uint32_t T = lo;
  int cl = 0;
  #pragma unroll
  for (int j = 0; j < 64; j++) cl += (ku[j] < T) ? 1 : 0;
  int incl = cl;
  #pragma unroll
  for (int off = 1; off < 64; off <<= 1) {
    int v = __shfl_up(incl, off);
    if (lane >= off) incl += v;
  }
  int nless = __shfl(incl, 63);
  int pos = incl - cl;
  __shared__ uint32_t selv[4][256];
  uint32_t* sv = selv[wv];
  #pragma unroll
  for (int g = 0; g < 4; g++) sv[g * 64 + lane] = 0xFFFFFFFFu;
  for (int p = nless + lane; p < 200; p += 64) sv[p] = T;
  #pragma unroll
  for (int j = 0; j < 64; j++)
    if (ku[j] < T) sv[pos++] = ku[j];
  uint32_t v[4];
  #pragma unroll
  for (int q = 0; q < 4; q++) v[q] = sv[q * 64 + lane];
  #pragma unroll
  for (int kk = 2; kk <= 256; kk <<= 1) {
    #pragma unroll
    for (int jj = kk >> 1; jj > 0; jj >>= 1) {
      if (jj >= 64) {
        int qb = jj >> 6;
        #pragma unroll
        for (int q = 0; q < 4; q++) {
          if ((q & qb) == 0) {
            int q2 = q | qb;
            bool up = (kk == 256) ? true : ((q & (kk >> 6)) == 0);
            uint32_t a = v[q], b2 = v[q2];
            uint32_t lo2 = min(a, b2), hi2 = max(a, b2);
            v[q] = up ? lo2 : hi2;
            v[q2] = up ? hi2 : lo2;
          }
        }
      } else {
        #pragma unroll
        for (int q = 0; q < 4; q++) {
          bool up;
          if (kk == 256) up = true;
          else if (kk == 128) up = ((q & 2) == 0);
          else if (kk == 64) up = ((q & 1) == 0);
          else up = ((lane & kk) == 0);
          uint32_t other = (uint32_t)__shfl_xor((int)v[q], jj);
          bool lower = ((lane & jj) == 0);
          uint32_t lo2 = min(v[q], other), hi2 = max(v[q], other);
          v[q] = (up == lower) ? lo2 : hi2;
        }
      }
    }
  }
  int grow = row_base + row_local;
  int b = grow >> 12, r = grow & 4095;
  #pragma unroll
  for (int q = 0; q < 4; q++) {
    int i = q * 64 + lane;
    if (i < 200) {
      uint32_t u = v[q] & 0xFFFFu;
      u ^= (u & 0x8000u) ? 0x8000u : 0xFFFFu;
      out[((size_t)b * 200 + i) * 4096 + r] = sqrtf(bf2f((u16)u));
    }
  }
}

extern "C" void kernel_launch(void* const* d_in, const int* in_sizes, int n_in,
                              void* d_out, int out_size, void* d_ws, size_t ws_size,
                              hipStream_t stream) {
  const float* p0 = (const float*)d_in[0];   // (4,256,64,64)
  const float* p1 = (const float*)d_in[1];   // (4,512,32,32)
  const float* p2 = (const float*)d_in[2];   // (4,1024,16,16)
  const float* w1 = (const float*)d_in[5];   // (256,258)
  const float* b1 = (const float*)d_in[6];
  const float* w2 = (const float*)d_in[7];   // (512,514)
  const float* b2 = (const float*)d_in[8];
  const float* w3 = (const float*)d_in[9];   // (1024,1026)
  const float* b3 = (const float*)d_in[10];
  const float* Cm = (const float*)d_in[11];  // (1792,4096)

  float* out_score = (float*)d_out;                  // 4*200*4096 fp32
  float* out_phi = (float*)d_out + 3276800;          // 4*896*4096 fp32

  // workspace layout (peak ~103.9 MB)
  char* w = (char*)d_ws;
  uint8_t* A8 = (uint8_t*)w;                         //  29,360,128 B [16384][1792] fp8
  uint8_t* Ct8 = (uint8_t*)(w + 29360128);           //   7,340,032 B [4096][1792] fp8
  float* feats = (float*)(w + 36700160);             //      65,536 B
  float* cents = (float*)(w + 36765696);             //      16,384 B
  u16* S16 = (u16*)(w + 36782080);                   //  67,108,864 B (bf16, 8192-row chunk) -> ends 103,890,944
  // stage-A temps alias the S16 region (dead before first gemm_dist2):
  u16* PT1 = (u16*)(w + 36782080);                   //   8,388,608 B [16384][256]
  u16* PT2 = (u16*)(w + 45170688);                   //   4,194,304 B [4096][512]
  u16* PT3 = (u16*)(w + 49364992);                   //   2,097,152 B [1024][1024]
  u16* Wbf1 = (u16*)(w + 51462144);                  //     131,072 B
  u16* Wbf2 = (u16*)(w + 51593216);                  //     524,288 B
  u16* Wbf3 = (u16*)(w + 52117504);                  //   2,097,152 B
  float* O2 = (float*)(w + 54214656);                //   8,388,608 B [4][512][1024]
  float* O3 = (float*)(w + 62603264);                //     524,288 B [4][128][256]
  u16* OT2 = (u16*)(w + 63127552);                   //   4,194,304 B [4][1024][512]
  u16* OT3 = (u16*)(w + 67321856);                   //   2,097,152 B [4][256][1024] -> ends 69,419,008

  // ---- fused pool + transpose + bf16 -> PT ----
  pool_trans<256, 64, 64><<<dim3(128, 8, 4), 256, 0, stream>>>(p0, PT1);
  pool_trans<512, 32, 32><<<dim3(32, 16, 4), 256, 0, stream>>>(p1, PT2);
  pool_trans<1024, 16, 16><<<dim3(8, 32, 4), 256, 0, stream>>>(p2, PT3);

  // ---- weights -> bf16 ----
  wconv_bf16<<<32, 256, 0, stream>>>(w1, Wbf1, 8, 8192);
  wconv_bf16<<<128, 256, 0, stream>>>(w2, Wbf2, 9, 32768);
  wconv_bf16<<<512, 256, 0, stream>>>(w3, Wbf3, 10, 131072);

  // ---- coordconv via MFMA GEMM, dual-layout epilogue ----
  conv_gemm<256, 4096, 64, 256, 256, 1792, true><<<dim3(128, 2), 256, 0, stream>>>(
      Wbf1, PT1, w1, b1, out_phi, (size_t)896 * 4096, A8);
  conv_gemm<512, 1024, 32, 512, 512, 512, false><<<dim3(32, 4), 256, 0, stream>>>(
      Wbf2, PT2, w2, b2, O2, (size_t)512 * 1024, OT2);
  conv_gemm<1024, 256, 16, 1024, 128, 1024, false><<<dim3(8, 8), 256, 0, stream>>>(
      Wbf3, PT3, w3, b3, O3, (size_t)128 * 256, OT3);

  // ---- out_phi levels 2,3 (bilinear resize) ----
  emit_phi_v<512, 512, 32><<<8192, 256, 0, stream>>>(O2, out_phi, 256);
  emit_phi_v<128, 128, 16><<<2048, 256, 0, stream>>>(O3, out_phi, 768);

  // ---- A8 cols [256,1792): coalesced gather from OT (bf16 taps -> fp8) ----
  gather_A<512, 32, 6><<<4096, 256, 0, stream>>>(OT2, A8, 256);
  gather_A<1024, 16, 7><<<8192, 256, 0, stream>>>(OT3, A8, 768);

  // ---- C transpose -> fp8 (permuted cols) ----
  trans_f32_fp8<<<dim3(128, 56), 256, 0, stream>>>(Cm, Ct8, 1792, 4096, 1792);

  // ---- norms (from the SAME fp8 data the GEMM sees) ----
  rownorm8<<<4096, 256, 0, stream>>>(A8, feats, 1792);
  rownorm8<<<1024, 256, 0, stream>>>(Ct8, cents, 1792);

  // ---- fp8 distance GEMM (256x128 tile, 2 blocks/CU) + top-200, 2 chunks ----
  for (int mc = 0; mc < 2; mc++) {
    gemm_dist2<<<1024, 256, 49152, stream>>>(A8, Ct8, feats, cents, S16, mc * 8192);
    select_topk<<<2048, 256, 0, stream>>>(S16, out_score, mc * 8192);
  }
}